// Round 2
// baseline (54.645 us; speedup 1.0000x reference)
//
#include <hip/hip_runtime.h>

namespace {

template<int CTRL, int RM>
__device__ __forceinline__ float dpp_mov0(float v) {
  return __int_as_float(__builtin_amdgcn_update_dpp(
      0, __float_as_int(v), CTRL, RM, 0xF, false));
}
template<int CTRL, int RM>
__device__ __forceinline__ float dpp_mov1(float v) {
  return __int_as_float(__builtin_amdgcn_update_dpp(
      0x3f800000, __float_as_int(v), CTRL, RM, 0xF, false));
}

// ---- fused A_bar apply -----------------------------------------------------
// lhs = I - h*A = diag(d_n) + h*r_i*r_k (k<i), h = dt/2, r_n = sqrt(2n+1),
// d_n = 1 + h(n+1).  y = A_bar x = lhs^{-1}(2I - lhs)x collapses to ONE joint
// 2x2 lower-triangular linear-recurrence scan over (S_i, T_i):
//   S_i = S_{i-1} + r_i x_i                      (prefix sum of r x)
//   T_i = g_i T_{i-1} - (h r_i^2/d_i) S_{i-1} + (r_i tmd_i/d_i) x_i
// with g_i=(1-h i)/d_i, tmd_i=2-d_i; then y_i = inv_d*(alpha_i x_i - h r_i (S_i + T_{i-1})),
// alpha_i = 1 + h i.  Scan element per lane: M=[[1,0],[c,g]], b=[w1;w2],
// c = g - 1 (= -h r^2/d), w1 = r x, w2 = (r tmd/d) x.
struct Coef {
  float r, inv_d, hr, g0, c0, alpha, k2;
};

__device__ __forceinline__ Coef make_coef(float dt, int n) {
  float h = 0.5f * dt, fn = (float)n;
  float r = sqrtf(2.f * fn + 1.f);
  float d = 1.f + h * (fn + 1.f);
  float inv_d = 1.f / d;
  float g0 = (1.f - h * fn) * inv_d;
  Coef c;
  c.r = r; c.inv_d = inv_d; c.hr = h * r;
  c.g0 = g0; c.c0 = g0 - 1.f;           // = -h r^2 / d
  c.alpha = 1.f + h * fn;
  c.k2 = r * (2.f - d) * inv_d;
  return c;
}

// one combine step of the (c,g,w1,w2) scan; identity = (0,1,0,0)
template<int CTRL, int RM>
__device__ __forceinline__ void fused_step(float& c, float& g, float& w1, float& w2) {
  float cP  = dpp_mov0<CTRL, RM>(c);
  float gP  = dpp_mov1<CTRL, RM>(g);
  float w1P = dpp_mov0<CTRL, RM>(w1);
  float w2P = dpp_mov0<CTRL, RM>(w2);
  w2 = fmaf(g, w2P, fmaf(c, w1P, w2));  // uses old c, old g
  c  = fmaf(g, cP, c);                  // uses old g
  g  = g * gP;
  w1 = w1 + w1P;
}

__device__ __forceinline__ float abar_apply(float x, const Coef& c) {
  float cc = c.c0, g = c.g0, w1 = c.r * x, w2 = c.k2 * x;
  fused_step<0x111, 0xF>(cc, g, w1, w2);   // row_shr:1
  fused_step<0x112, 0xF>(cc, g, w1, w2);   // row_shr:2
  fused_step<0x114, 0xF>(cc, g, w1, w2);   // row_shr:4
  fused_step<0x118, 0xF>(cc, g, w1, w2);   // row_shr:8
  fused_step<0x142, 0xA>(cc, g, w1, w2);   // row_bcast15 -> rows 1,3
  fused_step<0x143, 0xC>(cc, g, w1, w2);   // row_bcast31 -> rows 2,3
  float tp = dpp_mov0<0x138, 0xF>(w2);     // wave_shr:1 -> T_{i-1} (lane0 -> 0)
  return c.inv_d * fmaf(-c.hr, w1 + tp, c.alpha * x);
}

// plain linear-recurrence scan (for the single B_bar solve)
template<int CTRL, int RM>
__device__ __forceinline__ void linrec_step(float& G, float& W) {
  float Wo = dpp_mov0<CTRL, RM>(W);
  float Go = dpp_mov1<CTRL, RM>(G);
  W = fmaf(G, Wo, W);
  G *= Go;
}
__device__ __forceinline__ float lhs_solve(float z, const Coef& c) {
  float G = c.g0, W = c.r * z * c.inv_d;
  linrec_step<0x111, 0xF>(G, W);
  linrec_step<0x112, 0xF>(G, W);
  linrec_step<0x114, 0xF>(G, W);
  linrec_step<0x118, 0xF>(G, W);
  linrec_step<0x142, 0xA>(G, W);
  linrec_step<0x143, 0xC>(G, W);
  float sp = dpp_mov0<0x138, 0xF>(W);      // wave_shr:1
  return (z - c.hr * sp) * c.inv_d;
}

__device__ __forceinline__ float softplus_dt(float ldt) {
  return log1pf(expf(ldt)) + 1e-6f;
}

// dense 64-MAC matvec: result[lane] = sum_k pc[k] * u_k  (pc register-resident)
__device__ __forceinline__ float qapply(const float (&pc)[64], float u) {
  float a0 = 0.f, a1 = 0.f, a2 = 0.f, a3 = 0.f;
  #pragma unroll
  for (int k = 0; k < 64; k += 4) {
    float u0 = __int_as_float(__builtin_amdgcn_readlane(__float_as_int(u), k + 0));
    float u1 = __int_as_float(__builtin_amdgcn_readlane(__float_as_int(u), k + 1));
    float u2 = __int_as_float(__builtin_amdgcn_readlane(__float_as_int(u), k + 2));
    float u3 = __int_as_float(__builtin_amdgcn_readlane(__float_as_int(u), k + 3));
    a0 = fmaf(pc[k + 0], u0, a0);
    a1 = fmaf(pc[k + 1], u1, a1);
    a2 = fmaf(pc[k + 2], u2, a2);
    a3 = fmaf(pc[k + 3], u3, a3);
  }
  return (a0 + a1) + (a2 + a3);
}

__device__ __forceinline__ void load_row(const float* __restrict__ base, float (&pc)[64]) {
  const float4* p4 = (const float4*)base;
  #pragma unroll
  for (int q = 0; q < 16; ++q) {
    float4 f = p4[q];
    pc[4*q+0] = f.x; pc[4*q+1] = f.y; pc[4*q+2] = f.z; pc[4*q+3] = f.w;
  }
}

} // namespace

// Kernel 1: PT[a][b] = P[b][a], P = A_bar^64. Block m runs the chain on e_m.
__global__ __launch_bounds__(64) void hippo_pow64(const float* __restrict__ ldt_p,
                                                  float* __restrict__ PT) {
  const int lane = threadIdx.x;
  const int m = blockIdx.x;
  const float dt = softplus_dt(ldt_p[0]);
  const Coef c = make_coef(dt, lane);
  float x = (lane == m) ? 1.f : 0.f;
  for (int s = 0; s < 64; ++s) x = abar_apply(x, c);
  PT[m * 64 + lane] = x;   // coalesced
}

// Kernel 2: Q2[row][col] = (P^T P^T)[row][col].  Block m computes column m.
__global__ __launch_bounds__(64) void hippo_q2(const float* __restrict__ PT,
                                               float* __restrict__ Q2) {
  const int lane = threadIdx.x;
  const int m = blockIdx.x;
  float pc[64];
  load_row(PT + lane * 64, pc);            // pc[k] = P[k][lane]
  float u = PT[lane * 64 + m];             // u = col m of Q (= P[m][:])
  float v = qapply(pc, u);                 // v = Q^2 e_m
  Q2[lane * 64 + m] = v;                   // row-major Q^2
}

// Kernel 3: per d — wave0: V chain (64 scans); wave1/2: even/odd U chains
// (16 matvecs each via Q^2); all 4 waves: 32x64 dot epilogue.
__global__ __launch_bounds__(256) void hippo_main(
    const float* __restrict__ B, const float* __restrict__ C,
    const float* __restrict__ Dv, const float* __restrict__ ldt_p,
    const float* __restrict__ PT, const float* __restrict__ Q2,
    float* __restrict__ out, int NI, int L) {
  __shared__ __align__(16) float Vl[64 * 65];  // pad 65 -> conflict-free
  __shared__ __align__(16) float Ul[32 * 64];
  const int d = blockIdx.x;
  const int tau = threadIdx.x;
  const int lane = tau & 63;
  const int w = tau >> 6;
  const float dt = softplus_dt(ldt_p[0]);
  const Coef c = make_coef(dt, lane);

  if (w == 0) {
    // B_bar[d] = lhs^{-1}(dt B[d]); v_{j+1} = A_bar v_j
    float v = lhs_solve(dt * B[d * 64 + lane], c);
    for (int j = 0; j < 64; ++j) {
      Vl[j * 65 + lane] = v;
      if (j < 63) v = abar_apply(v, c);
    }
  } else if (w == 1) {
    // even u's: u_0, u_2, ... via Q^2
    float pc[64];
    load_row(Q2 + lane * 64, pc);
    float u = C[d * 64 + lane];
    const int nE = (NI + 1) >> 1;
    for (int a = 0; a < nE; ++a) {
      Ul[(2 * a) * 64 + lane] = u;
      if (a < nE - 1) u = qapply(pc, u);
    }
  } else if (w == 2) {
    // odd u's: u_1 = Q u_0, then via Q^2
    float pc[64];
    load_row(PT + lane * 64, pc);          // pc[k] = P[k][lane] -> applies Q=P^T
    float u = C[d * 64 + lane];
    u = qapply(pc, u);                     // u_1
    load_row(Q2 + lane * 64, pc);          // reuse registers
    const int nO = NI >> 1;
    for (int a = 0; a < nO; ++a) {
      Ul[(2 * a + 1) * 64 + lane] = u;
      if (a < nO - 1) u = qapply(pc, u);
    }
  }
  __syncthreads();

  // Epilogue: K[d, i*64+j] = dot(U[i], V[j]); thread -> j=lane, i = w + 4k.
  // Two 32-wide halves to keep peak VGPR low (all 1024 blocks resident).
  const int j = lane;
  float acc[8];
  #pragma unroll
  for (int k = 0; k < 8; ++k) acc[k] = 0.f;
  #pragma unroll
  for (int h = 0; h < 2; ++h) {
    float vr[32];
    #pragma unroll
    for (int n = 0; n < 32; ++n) vr[n] = Vl[j * 65 + h * 32 + n];
    #pragma unroll
    for (int k = 0; k < 8; ++k) {
      const int i = w + 4 * k;
      if (i < NI) {
        const float4* u4 = (const float4*)(Ul + i * 64 + h * 32);  // uniform -> broadcast
        float a0 = 0.f, a1 = 0.f, a2 = 0.f, a3 = 0.f;
        #pragma unroll
        for (int q = 0; q < 8; ++q) {
          float4 f = u4[q];
          a0 = fmaf(vr[4*q+0], f.x, a0);
          a1 = fmaf(vr[4*q+1], f.y, a1);
          a2 = fmaf(vr[4*q+2], f.z, a2);
          a3 = fmaf(vr[4*q+3], f.w, a3);
        }
        acc[k] += (a0 + a1) + (a2 + a3);
      }
    }
  }
  #pragma unroll
  for (int k = 0; k < 8; ++k) {
    const int i = w + 4 * k;
    if (i < NI) {
      float y = acc[k];
      if ((i | j) == 0) y += Dv[d];
      out[(size_t)d * L + i * 64 + j] = y;   // coalesced
    }
  }
}

extern "C" void kernel_launch(void* const* d_in, const int* in_sizes, int n_in,
                              void* d_out, int out_size, void* d_ws, size_t ws_size,
                              hipStream_t stream) {
  const float* B   = (const float*)d_in[0];
  const float* C   = (const float*)d_in[1];
  const float* Dv  = (const float*)d_in[2];
  const float* ldt = (const float*)d_in[3];
  const int d_model = in_sizes[2];        // 1024
  const int L = out_size / d_model;       // 2048
  const int NI = L / 64;                  // 32
  float* PT = (float*)d_ws;               // 16 KiB
  float* Q2 = (float*)d_ws + 64 * 64;     // 16 KiB
  hippo_pow64<<<64, 64, 0, stream>>>(ldt, PT);
  hippo_q2<<<64, 64, 0, stream>>>(PT, Q2);
  hippo_main<<<d_model, 256, 0, stream>>>(B, C, Dv, ldt, PT, Q2, (float*)d_out, NI, L);
}

// Round 3
// 44.792 us; speedup vs baseline: 1.2200x; 1.2200x over previous
//
#include <hip/hip_runtime.h>

namespace {

template<int CTRL, int RM>
__device__ __forceinline__ float dpp_mov0(float v) {
  return __int_as_float(__builtin_amdgcn_update_dpp(
      0, __float_as_int(v), CTRL, RM, 0xF, false));
}
template<int CTRL, int RM>
__device__ __forceinline__ float dpp_mov1(float v) {
  return __int_as_float(__builtin_amdgcn_update_dpp(
      0x3f800000, __float_as_int(v), CTRL, RM, 0xF, false));
}

// lhs = I - h*A = diag(d_n) + h r_i r_k (k<i), h=dt/2, r_n=sqrt(2n+1),
// d_n = 1+h(n+1). y = A_bar x collapses to one 2x2 lower-triangular
// linear-recurrence scan over (S,T) (verified on HW in round 2). The scan's
// per-lane matrix entries (c,g) are DATA-INDEPENDENT -> hoist the 6 per-step
// snapshots once per wave; each apply then costs 2 DPP + 3 VALU per step.
struct Hoist {
  float cs0, cs1, cs2, cs3, cs4, cs5;
  float gs0, gs1, gs2, gs3, gs4, gs5;
  float r, inv_d, hr, alpha, k2;
};

__device__ __forceinline__ Hoist make_hoist(float dt, int n) {
  float h = 0.5f * dt, fn = (float)n;
  float r = sqrtf(2.f * fn + 1.f);
  float d = 1.f + h * (fn + 1.f);
  float inv_d = 1.f / d;
  float g = (1.f - h * fn) * inv_d;
  float c = g - 1.f;                  // = -h r^2 / d
  Hoist H;
  H.r = r; H.inv_d = inv_d; H.hr = h * r;
  H.alpha = 1.f + h * fn;
  H.k2 = r * (2.f - d) * inv_d;
#define COEF_STEP(IDX, CTRL, RM)                                        \
  H.cs##IDX = c; H.gs##IDX = g;                                         \
  { float cP = dpp_mov0<CTRL, RM>(c);                                   \
    float gP = dpp_mov1<CTRL, RM>(g);                                   \
    c = fmaf(g, cP, c); g = g * gP; }
  COEF_STEP(0, 0x111, 0xF)   // row_shr:1
  COEF_STEP(1, 0x112, 0xF)   // row_shr:2
  COEF_STEP(2, 0x114, 0xF)   // row_shr:4
  COEF_STEP(3, 0x118, 0xF)   // row_shr:8
  COEF_STEP(4, 0x142, 0xA)   // row_bcast15 -> rows 1,3
  COEF_STEP(5, 0x143, 0xC)   // row_bcast31 -> rows 2,3
#undef COEF_STEP
  return H;
}

__device__ __forceinline__ float abar_apply(float x, const Hoist& H) {
  float w1 = H.r * x, w2 = H.k2 * x;
#define APPLY_STEP(IDX, CTRL, RM)                                       \
  { float w1P = dpp_mov0<CTRL, RM>(w1);                                 \
    float w2P = dpp_mov0<CTRL, RM>(w2);                                 \
    w2 = fmaf(H.cs##IDX, w1P, fmaf(H.gs##IDX, w2P, w2));                \
    w1 += w1P; }
  APPLY_STEP(0, 0x111, 0xF)
  APPLY_STEP(1, 0x112, 0xF)
  APPLY_STEP(2, 0x114, 0xF)
  APPLY_STEP(3, 0x118, 0xF)
  APPLY_STEP(4, 0x142, 0xA)
  APPLY_STEP(5, 0x143, 0xC)
#undef APPLY_STEP
  float tp = dpp_mov0<0x138, 0xF>(w2);           // wave_shr:1 -> T_{i-1}
  return H.inv_d * fmaf(-H.hr, w1 + tp, H.alpha * x);
}

// plain linear-recurrence scan for the one-time B_bar solve
template<int CTRL, int RM>
__device__ __forceinline__ void linrec_step(float& G, float& W) {
  float Wo = dpp_mov0<CTRL, RM>(W);
  float Go = dpp_mov1<CTRL, RM>(G);
  W = fmaf(G, Wo, W);
  G *= Go;
}
__device__ __forceinline__ float lhs_solve(float z, const Hoist& H) {
  float G = H.gs0, W = H.r * z * H.inv_d;
  linrec_step<0x111, 0xF>(G, W);
  linrec_step<0x112, 0xF>(G, W);
  linrec_step<0x114, 0xF>(G, W);
  linrec_step<0x118, 0xF>(G, W);
  linrec_step<0x142, 0xA>(G, W);
  linrec_step<0x143, 0xC>(G, W);
  float sp = dpp_mov0<0x138, 0xF>(W);
  return (z - H.hr * sp) * H.inv_d;
}

__device__ __forceinline__ float softplus_dt(float ldt) {
  return log1pf(expf(ldt)) + 1e-6f;
}

__device__ __forceinline__ void load_row(const float* __restrict__ base,
                                         float (&pc)[64]) {
  const float4* p4 = (const float4*)base;
  #pragma unroll
  for (int q = 0; q < 16; ++q) {
    float4 f = p4[q];
    pc[4*q+0] = f.x; pc[4*q+1] = f.y; pc[4*q+2] = f.z; pc[4*q+3] = f.w;
  }
}

// dense matvec from a per-lane register value (readlane broadcast)
__device__ __forceinline__ float qapply(const float (&pc)[64], float u) {
  float a0 = 0.f, a1 = 0.f, a2 = 0.f, a3 = 0.f;
  #pragma unroll
  for (int k = 0; k < 64; k += 4) {
    float u0 = __int_as_float(__builtin_amdgcn_readlane(__float_as_int(u), k + 0));
    float u1 = __int_as_float(__builtin_amdgcn_readlane(__float_as_int(u), k + 1));
    float u2 = __int_as_float(__builtin_amdgcn_readlane(__float_as_int(u), k + 2));
    float u3 = __int_as_float(__builtin_amdgcn_readlane(__float_as_int(u), k + 3));
    a0 = fmaf(pc[k + 0], u0, a0);
    a1 = fmaf(pc[k + 1], u1, a1);
    a2 = fmaf(pc[k + 2], u2, a2);
    a3 = fmaf(pc[k + 3], u3, a3);
  }
  return (a0 + a1) + (a2 + a3);
}

// dense matvec where the source vector sits in an LDS row (uniform broadcast
// ds_read_b128 -> no cross-lane ops, co-issues with VALU)
__device__ __forceinline__ float lds_matvec(const float (&pc)[64],
                                            const float* row) {
  const float4* r4 = (const float4*)row;
  float a0 = 0.f, a1 = 0.f, a2 = 0.f, a3 = 0.f;
  #pragma unroll
  for (int q = 0; q < 16; ++q) {
    float4 f = r4[q];
    a0 = fmaf(pc[4*q+0], f.x, a0);
    a1 = fmaf(pc[4*q+1], f.y, a1);
    a2 = fmaf(pc[4*q+2], f.z, a2);
    a3 = fmaf(pc[4*q+3], f.w, a3);
  }
  return (a0 + a1) + (a2 + a3);
}

} // namespace

// Prep (ONE kernel): block m chains e_m through 128 applies.
//   s=32 : col m of A32  -> scatter into row-major A32c   (A32c[n][k]=A32[n][k])
//   s=64 : col m of A64  = row m of Q=P64^T  -> QROW  (coalesced)
//   s=128: col m of A128 = row m of Q^2      -> Q2ROW (coalesced)
__global__ __launch_bounds__(64) void hippo_pow(const float* __restrict__ ldt_p,
                                                float* __restrict__ A32c,
                                                float* __restrict__ QROW,
                                                float* __restrict__ Q2ROW) {
  const int lane = threadIdx.x;
  const int m = blockIdx.x;
  const float dt = softplus_dt(ldt_p[0]);
  const Hoist H = make_hoist(dt, lane);
  float x = (lane == m) ? 1.f : 0.f;
  #pragma unroll 1
  for (int s = 0; s < 32; ++s) x = abar_apply(x, H);
  A32c[lane * 64 + m] = x;               // scattered, 16 KB total: fine
  #pragma unroll 1
  for (int s = 0; s < 32; ++s) x = abar_apply(x, H);
  QROW[m * 64 + lane] = x;
  #pragma unroll 1
  for (int s = 0; s < 64; ++s) x = abar_apply(x, H);
  Q2ROW[m * 64 + lane] = x;
}

// Main: 4-way chain split, then 32x64 dot epilogue.
//  wave0: V[0..31]   (lhs_solve + 31 applies)
//  wave3: V[32..63]  (lhs_solve + A32 matvec + 31 applies)
//  wave1: U even     (15 Q^2 LDS-matvecs)
//  wave2: U odd      (1 Q readlane-matvec + 15 Q^2 LDS-matvecs)
__global__ __launch_bounds__(256, 4) void hippo_main(
    const float* __restrict__ B, const float* __restrict__ C,
    const float* __restrict__ Dv, const float* __restrict__ ldt_p,
    const float* __restrict__ A32c, const float* __restrict__ QROW,
    const float* __restrict__ Q2ROW, float* __restrict__ out, int NI, int L) {
  __shared__ __align__(16) float Vl[64 * 65];  // pad 65 -> conflict-free reads
  __shared__ __align__(16) float Ul[32 * 64];
  const int d = blockIdx.x;
  const int tau = threadIdx.x;
  const int lane = tau & 63;
  const int w = tau >> 6;
  const float dt = softplus_dt(ldt_p[0]);
  const Hoist H = make_hoist(dt, lane);

  if (w == 0) {
    float v = lhs_solve(dt * B[d * 64 + lane], H);
    #pragma unroll 1
    for (int j = 0; j < 32; ++j) {
      Vl[j * 65 + lane] = v;
      if (j < 31) v = abar_apply(v, H);
    }
  } else if (w == 3) {
    float bb = lhs_solve(dt * B[d * 64 + lane], H);
    float pc[64];
    load_row(A32c + lane * 64, pc);       // pc[k] = A32[lane][k]
    float v = qapply(pc, bb);             // V32 = A32 * B_bar
    #pragma unroll 1
    for (int j = 32; j < 64; ++j) {
      Vl[j * 65 + lane] = v;
      if (j < 63) v = abar_apply(v, H);
    }
  } else if (w == 1) {
    float pc[64];
    load_row(Q2ROW + lane * 64, pc);      // pc[k] = Q2[lane][k]
    float u = C[d * 64 + lane];
    const int nE = (NI + 1) >> 1;
    #pragma unroll 1
    for (int a = 0; a < nE; ++a) {
      Ul[(2 * a) * 64 + lane] = u;
      if (a < nE - 1) u = lds_matvec(pc, Ul + (2 * a) * 64);
    }
  } else {  // w == 2
    float pc[64];
    load_row(QROW + lane * 64, pc);       // pc[k] = Q[lane][k]
    float u = qapply(pc, C[d * 64 + lane]);   // u1 = Q u0 (register source)
    load_row(Q2ROW + lane * 64, pc);
    const int nO = NI >> 1;
    #pragma unroll 1
    for (int a = 0; a < nO; ++a) {
      Ul[(2 * a + 1) * 64 + lane] = u;
      if (a < nO - 1) u = lds_matvec(pc, Ul + (2 * a + 1) * 64);
    }
  }
  __syncthreads();

  // Epilogue: K[d, i*64+j] = dot(U[i], V[j]); j = lane, i = w + 4k.
  const int j = lane;
  float vr[64];
  #pragma unroll
  for (int n = 0; n < 64; ++n) vr[n] = Vl[j * 65 + n];
  #pragma unroll
  for (int k = 0; k < 8; ++k) {
    const int i = w + 4 * k;
    if (i < NI) {
      const float4* u4 = (const float4*)(Ul + i * 64);  // uniform -> broadcast
      float a0 = 0.f, a1 = 0.f, a2 = 0.f, a3 = 0.f;
      #pragma unroll
      for (int q = 0; q < 16; ++q) {
        float4 f = u4[q];
        a0 = fmaf(vr[4*q+0], f.x, a0);
        a1 = fmaf(vr[4*q+1], f.y, a1);
        a2 = fmaf(vr[4*q+2], f.z, a2);
        a3 = fmaf(vr[4*q+3], f.w, a3);
      }
      float y = (a0 + a1) + (a2 + a3);
      if ((i | j) == 0) y += Dv[d];
      out[(size_t)d * L + i * 64 + j] = y;   // coalesced
    }
  }
}

extern "C" void kernel_launch(void* const* d_in, const int* in_sizes, int n_in,
                              void* d_out, int out_size, void* d_ws, size_t ws_size,
                              hipStream_t stream) {
  const float* B   = (const float*)d_in[0];
  const float* C   = (const float*)d_in[1];
  const float* Dv  = (const float*)d_in[2];
  const float* ldt = (const float*)d_in[3];
  const int d_model = in_sizes[2];        // 1024
  const int L = out_size / d_model;       // 2048
  const int NI = L / 64;                  // 32
  float* A32c  = (float*)d_ws;            // 16 KiB
  float* QROW  = (float*)d_ws + 4096;     // 16 KiB
  float* Q2ROW = (float*)d_ws + 8192;     // 16 KiB
  hippo_pow<<<64, 64, 0, stream>>>(ldt, A32c, QROW, Q2ROW);
  hippo_main<<<d_model, 256, 0, stream>>>(B, C, Dv, ldt, A32c, QROW, Q2ROW,
                                          (float*)d_out, NI, L);
}